// Round 1
// baseline (10116.756 us; speedup 1.0000x reference)
//
#include <hip/hip_runtime.h>
#include <stdint.h>

#define B_   64
#define N_   256
#define S_   2000
#define K_   100
#define BIL_ 4
#define NITER_ 200
#define JITTER_ 1e-4f
#define SAFETY_ 0.5f
#define PART_ 8
#define SCH_  (S_ / PART_)   // 250 scenarios per block

// ---- ws layout (offsets in float units) ----
#define OFF_LC16  ((size_t)0)                                   // bf16 L col-major
#define OFF_LR16  (OFF_LC16 + (size_t)B_ * N_ * N_ / 2)         // bf16 L row-major
#define OFF_EPST  (OFF_LR16 + (size_t)B_ * N_ * N_ / 2)         // bf16 epsT[b][n][s]
#define OFF_EPSRM (OFF_EPST + (size_t)B_ * N_ * S_ / 2)         // bf16 eps[b][s][n] (& temp fp32 Lc)
#define OFF_LOSS  (OFF_EPSRM + (size_t)B_ * S_ * N_ / 2)        // uint loss keys, double-buffered
#define OFF_BAR   (OFF_LOSS + (size_t)2 * B_ * S_)              // int barrier counters

// ---------------- helpers ----------------
__device__ __forceinline__ float wred_f(float x) {
#pragma unroll
  for (int off = 32; off > 0; off >>= 1) x += __shfl_xor(x, off);
  return x;
}
__device__ __forceinline__ int wred_i(int x) {
#pragma unroll
  for (int off = 32; off > 0; off >>= 1) x += __shfl_xor(x, off);
  return x;
}
// monotone key: larger loss -> SMALLER key (top-K largest = K smallest keys)
__device__ __forceinline__ unsigned keyd(float x) {
  unsigned u = __float_as_uint(x);
  unsigned ku = (u & 0x80000000u) ? ~u : (u | 0x80000000u);
  return ~ku;
}
__device__ __forceinline__ uint16_t f2b(float f) {  // RNE fp32->bf16
  uint32_t u = __float_as_uint(f);
  uint32_t r = u + 0x7FFFu + ((u >> 16) & 1u);
  return (uint16_t)(r >> 16);
}
__device__ __forceinline__ float blo(uint32_t u) { return __uint_as_float(u << 16); }
__device__ __forceinline__ float bhi(uint32_t u) { return __uint_as_float(u & 0xFFFF0000u); }

// Michelot exact simplex projection (fixed point == reference sort formula); one wave.
__device__ __forceinline__ float michelot4(const float vp[4], float z) {
  bool act[4] = {true, true, true, true};
  float theta = 0.0f;
  int prev = -1;
  for (int pass = 0; pass < 300; ++pass) {
    float ls = 0.0f; int lc = 0;
#pragma unroll
    for (int j = 0; j < 4; ++j) { if (act[j]) { ls += vp[j]; lc += 1; } }
    ls = wred_f(ls);
    lc = wred_i(lc);
    theta = (ls - z) / (float)lc;
    if (lc == prev) break;
    prev = lc;
#pragma unroll
    for (int j = 0; j < 4; ++j) act[j] = (vp[j] > theta);
  }
  return theta;
}

__device__ __forceinline__ void proj_store(const float y[4], float fl_bil, float mass, float muf,
                                           const float* __restrict__ muB, int ln,
                                           float* w_s, float* c_sh) {
  float vp[4];
#pragma unroll
  for (int j = 0; j < 4; ++j) {
    const int n = 4 * ln + j;
    vp[j] = y[j] - ((n == BIL_) ? fl_bil : 0.0f);
  }
  const float theta = michelot4(vp, mass);
  const float4 m4 = *(const float4*)(muB + 4 * ln);
  const float mm[4] = {m4.x, m4.y, m4.z, m4.w};
  float wj[4];
  float cp = 0.0f;
#pragma unroll
  for (int j = 0; j < 4; ++j) {
    const int n = 4 * ln + j;
    wj[j] = fmaxf(vp[j] - theta, 0.0f) + ((n == BIL_) ? fl_bil : 0.0f);
    cp = fmaf(muf * mm[j], wj[j], cp);
  }
  cp = wred_f(cp);
  if (ln == 0) *c_sh = cp;
  *(float4*)(w_s + 4 * ln) = make_float4(wj[0], wj[1], wj[2], wj[3]);
}

// ---------------- Cholesky v3: one block (512 thr) per batch (proven r3) ----------------
__global__ __launch_bounds__(512) void chol_kernel(const float* __restrict__ sigma,
                                                   float* __restrict__ Lc) {
  const int b = blockIdx.x;
  const int tid = threadIdx.x;
  const int i = tid & 255;
  const int half = tid >> 8;
  const float* Sg = sigma + (size_t)b * N_ * N_;
  float* L = Lc + (size_t)b * N_ * N_;
  __shared__ __align__(16) float slab[248 * 8];
  __shared__ __align__(16) float spart[256][8];
  __shared__ __align__(16) float pnl[64];

  for (int j0 = 0; j0 < N_; j0 += 8) {
    for (int x = tid; x < j0 * 8; x += 512) {
      const int k = x >> 3, jj = x & 7;
      slab[x] = L[(size_t)k * N_ + (j0 + jj)];
    }
    float s[8];
    if (half == 0) {
#pragma unroll
      for (int jj = 0; jj < 8; ++jj) {
        float a = Sg[(size_t)(j0 + jj) * N_ + i];
        if (i == j0 + jj) a += JITTER_;
        s[jj] = a;
      }
    } else {
#pragma unroll
      for (int jj = 0; jj < 8; ++jj) s[jj] = 0.0f;
    }
    __syncthreads();

    const int kb = half ? (j0 >> 1) : 0;
    const int ke = half ? j0 : (j0 >> 1);
#pragma unroll 4
    for (int k = kb; k < ke; ++k) {
      const float lk = L[(size_t)k * N_ + i];
      const float4 h0 = *(const float4*)&slab[k * 8];
      const float4 h1 = *(const float4*)&slab[k * 8 + 4];
      s[0] = fmaf(-lk, h0.x, s[0]);
      s[1] = fmaf(-lk, h0.y, s[1]);
      s[2] = fmaf(-lk, h0.z, s[2]);
      s[3] = fmaf(-lk, h0.w, s[3]);
      s[4] = fmaf(-lk, h1.x, s[4]);
      s[5] = fmaf(-lk, h1.y, s[5]);
      s[6] = fmaf(-lk, h1.z, s[6]);
      s[7] = fmaf(-lk, h1.w, s[7]);
    }
    if (half == 1) {
      *(float4*)&spart[i][0] = make_float4(s[0], s[1], s[2], s[3]);
      *(float4*)&spart[i][4] = make_float4(s[4], s[5], s[6], s[7]);
    }
    __syncthreads();

    if (half == 0) {
      const float4 p0 = *(const float4*)&spart[i][0];
      const float4 p1 = *(const float4*)&spart[i][4];
      s[0] += p0.x; s[1] += p0.y; s[2] += p0.z; s[3] += p0.w;
      s[4] += p1.x; s[5] += p1.y; s[6] += p1.z; s[7] += p1.w;
      if ((i >> 3) == (j0 >> 3)) {
        const int base = j0 & 63;
        const int r = i & 7;
        float l[8], di[8];
#pragma unroll
        for (int m = 0; m < 8; ++m) {
          const float smv = __shfl(s[m], base + m);
          const float d = sqrtf(smv);
          const float dinv = 1.0f / d;
          di[m] = dinv;
          float lm;
          if (r == m) lm = d;
          else if (r > m) lm = s[m] * dinv;
          else lm = 0.0f;
          l[m] = lm;
#pragma unroll
          for (int mm = m + 1; mm < 8; ++mm) {
            s[mm] = fmaf(-lm, __shfl(lm, base + mm), s[mm]);
          }
        }
#pragma unroll
        for (int m = 0; m < 8; ++m) pnl[r * 8 + m] = (m < r) ? l[m] : ((m == r) ? di[r] : 0.0f);
#pragma unroll
        for (int m = 0; m < 8; ++m) L[(size_t)(j0 + m) * N_ + i] = l[m];
      }
    }
    __syncthreads();

    if (half == 0 && (i >> 3) != (j0 >> 3)) {
      float l[8];
      if (i > j0) {
#pragma unroll
        for (int m = 0; m < 8; ++m) {
          float sm = s[m];
#pragma unroll
          for (int mm = 0; mm < 8; ++mm) {
            if (mm < m) sm = fmaf(-l[mm], pnl[m * 8 + mm], sm);
          }
          l[m] = sm * pnl[m * 8 + m];
        }
      } else {
#pragma unroll
        for (int m = 0; m < 8; ++m) l[m] = 0.0f;
      }
#pragma unroll
      for (int m = 0; m < 8; ++m) L[(size_t)(j0 + m) * N_ + i] = l[m];
    }
    __syncthreads();
  }
}

// ---------------- pack L ----------------
__global__ __launch_bounds__(256) void lpack_kernel(const float* __restrict__ Lc,
                                                    uint16_t* __restrict__ Lc16,
                                                    uint16_t* __restrict__ Lr16) {
  const int b = blockIdx.x;
  const float* Lp = Lc + (size_t)b * N_ * N_;
  uint16_t* C16 = Lc16 + (size_t)b * N_ * N_;
  uint16_t* R16 = Lr16 + (size_t)b * N_ * N_;
  __shared__ float tl[32][33];
  const int tx = threadIdx.x & 31;
  const int ty = threadIdx.x >> 5;
  for (int kt = 0; kt < 8; ++kt) {
    for (int it = 0; it < 8; ++it) {
#pragma unroll
      for (int rr = 0; rr < 4; ++rr) {
        const int k = kt * 32 + ty + 8 * rr;
        const int ii = it * 32 + tx;
        const float v = Lp[(size_t)k * N_ + ii];
        tl[ty + 8 * rr][tx] = v;
        C16[(size_t)k * N_ + ii] = f2b(v);
      }
      __syncthreads();
#pragma unroll
      for (int rr = 0; rr < 4; ++rr) {
        const int ii = it * 32 + ty + 8 * rr;
        const int k = kt * 32 + tx;
        R16[(size_t)ii * N_ + k] = f2b(tl[tx][ty + 8 * rr]);
      }
      __syncthreads();
    }
  }
}

// ---------------- eps -> bf16 both layouts; zero bar ----------------
__global__ __launch_bounds__(256) void etrans_kernel(const float* __restrict__ eps,
                                                     uint16_t* __restrict__ epsT16,
                                                     uint16_t* __restrict__ epsrm16,
                                                     int* __restrict__ bar) {
  const int b = blockIdx.x;
  const int s0 = blockIdx.y * 50;
  const int t = threadIdx.x;
  if (blockIdx.x == 0 && blockIdx.y == 0 && t < 64) bar[t] = 0;
  __shared__ float tl[50][257];
  const float* E = eps + ((size_t)b * S_ + s0) * N_;
  for (int p = 0; p < 50; ++p) tl[p][t] = E[(size_t)p * N_ + t];
  __syncthreads();
  uint16_t* RM = epsrm16 + ((size_t)b * S_ + s0) * N_;
  for (int p = 0; p < 50; ++p) RM[(size_t)p * N_ + t] = f2b(tl[p][t]);
  uint16_t* ET = epsT16 + (size_t)b * N_ * S_;
  const int g = t / 50, ss = t % 50;
  if (g < 5) {
    for (int q = 0; q < 52; ++q) {
      const int n = q * 5 + g;
      if (n < N_) ET[(size_t)n * S_ + s0 + ss] = f2b(tl[ss][n]);
    }
  }
}

// ---------------- solver: 8 blocks (1024 thr) per batch, grid 512, 2 blocks/CU ----------------
// r7 structure (register keys, 1-barrier radix passes, fused reduces) + r8: PART_ 4->8 so two
// independent blocks co-reside per CU (32/32 waves) and barrier/spin stalls of one block hide
// under the other's issue. launch_bounds(1024,8) pins VGPR<=64 to guarantee co-residency
// (spin-barrier liveness requires all 512 blocks resident; 512 = 256 CU x 2).
__global__ __launch_bounds__(1024, 8) void solve_kernel(
    const float* __restrict__ mu, const int* __restrict__ pcrisis,
    const int* __restrict__ plam, const uint16_t* __restrict__ Lc16,
    const uint16_t* __restrict__ Lr16, const uint16_t* __restrict__ epsT16,
    const uint16_t* __restrict__ epsrm16, unsigned* __restrict__ lossbits,
    int* __restrict__ bar, float* __restrict__ out) {
  const int bx = blockIdx.x;
  const int b = bx & (B_ - 1);
  const int part = bx >> 6;  // 0..7; blocks b+64k land on XCD b%8 under %8 RR
  const int t = threadIdx.x;
  const int ln = t & 63;
  const int s0 = part * SCH_;

  __shared__ __align__(16) float w_s[N_];
  __shared__ __align__(16) float v_s[N_];
  __shared__ __align__(16) float scratch[8][N_];  // matvec/stage1/e partials (flat-aliased)
  __shared__ __align__(16) uint16_t lists[S_];
  __shared__ __align__(16) int hist[4][256];      // one bank per radix pass
  __shared__ float c_sh;
  __shared__ int lcnt;
  __shared__ float sum_sh;

  const int crisis = pcrisis[0];
  const int lamv = plam[0];
  const float muf = 1.0f + ((lamv > 0) ? (1.0f / fmaxf((float)lamv, 0.1f)) : 0.0f);
  const float fl_bil = SAFETY_ * (float)crisis;
  const float mass = 1.0f - fl_bil;

  const uint16_t* LcB = Lc16 + (size_t)b * N_ * N_;
  const uint16_t* LrB = Lr16 + (size_t)b * N_ * N_;
  const float* muB = mu + (size_t)b * N_;
  const uint16_t* epsTB = epsT16 + (size_t)b * N_ * S_;
  const uint16_t* epsRB = epsrm16 + (size_t)b * S_ * N_;

  // ---- w0 = proj(uniform) ----
  if (t < 64) {
    float y[4];
#pragma unroll
    for (int j = 0; j < 4; ++j) y[j] = 1.0f / (float)N_;
    proj_store(y, fl_bil, mass, muf, muB, ln, w_s, &c_sh);
  }
  __syncthreads();  // B1

  for (int it = 0; it < NITER_; ++it) {
    // ---- v = L^T w partials: 8 i-octants x 128 k-pairs ----
    {
      const int oct = t >> 7, kp = t & 127;
      const uint32_t* Lp = (const uint32_t*)(LrB) + kp;
      const int i0 = 32 * oct;
      float a0 = 0.0f, a1 = 0.0f;
#pragma unroll 8
      for (int ii = 0; ii < 32; ++ii) {
        const uint32_t u = Lp[(size_t)(i0 + ii) * (N_ / 2)];
        const float ww = w_s[i0 + ii];
        a0 = fmaf(blo(u), ww, a0);
        a1 = fmaf(bhi(u), ww, a1);
      }
      *(float2*)&scratch[oct][2 * kp] = make_float2(a0, a1);
    }
    __syncthreads();  // B2

    // ---- v-reduce (t<256) + zero hist banks & lcnt (t>=256) ----
    if (t < N_) {
      v_s[t] = ((scratch[0][t] + scratch[1][t]) + (scratch[2][t] + scratch[3][t])) +
               ((scratch[4][t] + scratch[5][t]) + (scratch[6][t] + scratch[7][t]));
    } else {
      for (int x = t - 256; x < 4 * 256; x += 768) ((int*)hist)[x] = 0;
      if (t == 256) lcnt = 0;
    }
    __syncthreads();  // B3

    // ---- stage 1: partial losses for my 250 scenarios (8 n-octants x 125 pairs) ----
    const float cc = c_sh;
    {
      const int oct = t >> 7;    // n-octant (32 n)
      const int idx = t & 127;   // scenario-pair
      if (idx < SCH_ / 2) {
        const uint32_t* col = (const uint32_t*)(epsTB + (size_t)(32 * oct) * S_) + (s0 / 2 + idx);
        float a0 = 0.0f, a1 = 0.0f;
#pragma unroll 8
        for (int j = 0; j < 32; ++j) {
          const uint32_t u = col[(size_t)j * (S_ / 2)];
          const float vv = v_s[32 * oct + j];
          a0 = fmaf(blo(u), vv, a0);
          a1 = fmaf(bhi(u), vv, a1);
        }
        *(float2*)&scratch[oct][2 * idx] = make_float2(a0, a1);
      }
    }
    __syncthreads();  // B4

    // ---- combine + publish keys (relaxed agent atomics) ----
    unsigned* lgbuf = lossbits + ((it & 1) ? (size_t)B_ * S_ : 0) + (size_t)b * S_;
    if (t < SCH_) {
      const float lv = -(cc + (((scratch[0][t] + scratch[1][t]) + (scratch[2][t] + scratch[3][t])) +
                               ((scratch[4][t] + scratch[5][t]) + (scratch[6][t] + scratch[7][t]))));
      __hip_atomic_store(&lgbuf[s0 + t], keyd(lv), __ATOMIC_RELAXED, __HIP_MEMORY_SCOPE_AGENT);
    }
    __syncthreads();  // B5 (drains vmcnt before barrier exit)

    // ---- per-batch spin barrier (8 arrivals) ----
    if (t == 0) {
      __hip_atomic_fetch_add(&bar[b], 1, __ATOMIC_RELAXED, __HIP_MEMORY_SCOPE_AGENT);
      const int target = PART_ * (it + 1);
      while (__hip_atomic_load(&bar[b], __ATOMIC_RELAXED, __HIP_MEMORY_SCOPE_AGENT) < target) {
        __builtin_amdgcn_s_sleep(1);
      }
    }
    __syncthreads();  // B6

    // ---- gather all 2000 keys into registers (thread t owns scenarios 2t, 2t+1) + pass-0 hist ----
    uint32_t kx = 0xFFFFFFFFu, ky = 0xFFFFFFFFu;
    if (t < S_ / 2) {
      const unsigned long long two = __hip_atomic_load(
          (const unsigned long long*)(lgbuf + 2 * t), __ATOMIC_RELAXED, __HIP_MEMORY_SCOPE_AGENT);
      kx = (uint32_t)two;
      ky = (uint32_t)(two >> 32);
      atomicAdd(&hist[0][kx >> 24], 1);
      atomicAdd(&hist[0][ky >> 24], 1);
    }
    __syncthreads();  // B7

    // ---- 4-pass radix select: redundant all-wave scan (no publish barrier) ----
    unsigned pref = 0;
    int r = K_;
#pragma unroll
    for (int pass = 0; pass < 4; ++pass) {
      const int shift = 24 - 8 * pass;
      // redundant scan of hist[pass] by every wave
      {
        const int4 c4 = *(const int4*)&hist[pass][4 * ln];
        const int c0 = c4.x, c1 = c4.y, c2 = c4.z, c3 = c4.w;
        const int tot = c0 + c1 + c2 + c3;
        int sc = tot;
#pragma unroll
        for (int off = 1; off < 64; off <<= 1) {
          const int o = __shfl_up(sc, off);
          if (ln >= off) sc += o;
        }
        const int excl = sc - tot;
        const bool has = (excl < r) && (r <= sc);
        const unsigned long long bal = __ballot(has);
        const int lstar = __ffsll(bal) - 1;
        const int bc0 = __shfl(c0, lstar);
        const int bc1 = __shfl(c1, lstar);
        const int bc2 = __shfl(c2, lstar);
        const int bexcl = __shfl(excl, lstar);
        const int rr = r - bexcl;
        int d, rn;
        if (rr <= bc0) { d = 0; rn = rr; }
        else if (rr <= bc0 + bc1) { d = 1; rn = rr - bc0; }
        else if (rr <= bc0 + bc1 + bc2) { d = 2; rn = rr - bc0 - bc1; }
        else { d = 3; rn = rr - bc0 - bc1 - bc2; }
        pref |= (unsigned)(4 * lstar + d) << shift;
        r = rn;
      }
      if (pass < 3) {
        // next-pass histogram over prefix-matching keys (registers)
        const unsigned msk = 0xFFFFFFFFu << shift;
        const int nshift = shift - 8;
        if (t < S_ / 2) {
          if ((kx & msk) == pref) atomicAdd(&hist[pass + 1][(kx >> nshift) & 255], 1);
          if ((ky & msk) == pref) atomicAdd(&hist[pass + 1][(ky >> nshift) & 255], 1);
        }
      } else {
        // compact: selected = key <= pref (== loss >= K-th largest loss)
        if (t < S_ / 2) {
          if (kx <= pref) { const int p = atomicAdd(&lcnt, 1); lists[p] = (uint16_t)(2 * t); }
          if (ky <= pref) { const int p = atomicAdd(&lcnt, 1); lists[p] = (uint16_t)(2 * t + 1); }
        }
      }
      __syncthreads();  // B8..B11
    }

    const int cnt = lcnt;
    const float weight = 1.0f / (float)((cnt > K_) ? cnt : K_);

    // ---- e partials: 8 row-groups x 128 n-pairs ----
    {
      const int rt = t >> 7;
      const int np = t & 127;
      float a0 = 0.0f, a1 = 0.0f;
      for (int p = rt; p < cnt; p += 8) {
        const uint32_t u = *((const uint32_t*)(epsRB + (size_t)lists[p] * N_) + np);
        a0 += blo(u);
        a1 += bhi(u);
      }
      *(float2*)&scratch[rt][2 * np] = make_float2(a0, a1);
    }
    __syncthreads();  // B12

    // ---- e-reduce (wave 0): stash e in v_s ----
    if (t < 64) {
      float4 acc = make_float4(0.0f, 0.0f, 0.0f, 0.0f);
#pragma unroll
      for (int oct = 0; oct < 8; ++oct) {
        const float4 x = *(const float4*)&scratch[oct][4 * ln];
        acc.x += x.x; acc.y += x.y; acc.z += x.z; acc.w += x.w;
      }
      *(float4*)&v_s[4 * ln] = acc;
    }
    __syncthreads();  // B12b: e ready in v_s

    // ---- u = L e partials: 8 k-octants x 128 i-pairs ----
    {
      const int oct = t >> 7, ip = t & 127;
      const uint32_t* Lp = (const uint32_t*)(LcB) + ip;
      const int k0 = 32 * oct;
      float a0 = 0.0f, a1 = 0.0f;
#pragma unroll 8
      for (int kk = 0; kk < 32; ++kk) {
        const uint32_t u = Lp[(size_t)(k0 + kk) * (N_ / 2)];
        const float ee = v_s[k0 + kk];
        a0 = fmaf(blo(u), ee, a0);
        a1 = fmaf(bhi(u), ee, a1);
      }
      *(float2*)&scratch[oct][2 * ip] = make_float2(a0, a1);
    }
    __syncthreads();  // B13

    // ---- w update + projection (wave 0), u-reduce fused ----
    if (t < 64) {
      float4 u4 = make_float4(0.0f, 0.0f, 0.0f, 0.0f);
#pragma unroll
      for (int oct = 0; oct < 8; ++oct) {
        const float4 x = *(const float4*)&scratch[oct][4 * ln];
        u4.x += x.x; u4.y += x.y; u4.z += x.z; u4.w += x.w;
      }
      const float lr = 0.5f / sqrtf((float)it + 1.0f);
      const float4 w4 = *(const float4*)(w_s + 4 * ln);
      const float4 m4 = *(const float4*)(muB + 4 * ln);
      float y[4];
      y[0] = w4.x + lr * (muf * m4.x + u4.x * weight);
      y[1] = w4.y + lr * (muf * m4.y + u4.y * weight);
      y[2] = w4.z + lr * (muf * m4.z + u4.z * weight);
      y[3] = w4.w + lr * (muf * m4.w + u4.w * weight);
      proj_store(y, fl_bil, mass, muf, muB, ln, w_s, &c_sh);
    }
    __syncthreads();  // B14 (doubles as next iteration's B1)
  }

  // ---- output (part 0 only): w / (sum + 1e-8) ----
  if (part == 0) {
    if (t < 64) {
      const float4 w4 = *(const float4*)(w_s + 4 * ln);
      const float ssum = wred_f(w4.x + w4.y + w4.z + w4.w);
      if (ln == 0) sum_sh = ssum;
    }
    __syncthreads();
    if (t < N_) out[(size_t)b * N_ + t] = fmaxf(w_s[t], 0.0f) / (sum_sh + 1e-8f);
  }
}

extern "C" void kernel_launch(void* const* d_in, const int* in_sizes, int n_in,
                              void* d_out, int out_size, void* d_ws, size_t ws_size,
                              hipStream_t stream) {
  const float* mu = (const float*)d_in[0];
  const float* sigma = (const float*)d_in[1];
  const float* eps = (const float*)d_in[2];
  const int* crisis = (const int*)d_in[3];
  const int* lam = (const int*)d_in[4];
  float* out = (float*)d_out;
  float* ws = (float*)d_ws;

  uint16_t* Lc16 = (uint16_t*)(ws + OFF_LC16);
  uint16_t* Lr16 = (uint16_t*)(ws + OFF_LR16);
  uint16_t* epsT16 = (uint16_t*)(ws + OFF_EPST);
  uint16_t* epsrm16 = (uint16_t*)(ws + OFF_EPSRM);
  float* Lc = ws + OFF_EPSRM;  // fp32 L aliases epsrm16 (dead before etrans writes it)
  unsigned* lossbits = (unsigned*)(ws + OFF_LOSS);
  int* bar = (int*)(ws + OFF_BAR);

  chol_kernel<<<dim3(B_), dim3(512), 0, stream>>>(sigma, Lc);
  lpack_kernel<<<dim3(B_), dim3(256), 0, stream>>>(Lc, Lc16, Lr16);
  etrans_kernel<<<dim3(B_, S_ / 50), dim3(256), 0, stream>>>(eps, epsT16, epsrm16, bar);

  solve_kernel<<<dim3(PART_ * B_), dim3(1024), 0, stream>>>(
      mu, crisis, lam, Lc16, Lr16, epsT16, epsrm16, lossbits, bar, out);
}

// Round 2
// 5712.206 us; speedup vs baseline: 1.7711x; 1.7711x over previous
//
#include <hip/hip_runtime.h>
#include <stdint.h>

#define B_   64
#define N_   256
#define S_   2000
#define K_   100
#define BIL_ 4
#define NITER_ 200
#define JITTER_ 1e-4f
#define SAFETY_ 0.5f
#define PART_ 4
#define SCH_  (S_ / PART_)   // 500 scenarios per block

// ---- ws layout (offsets in float units) ----
#define OFF_LC16  ((size_t)0)                                   // bf16 L col-major (unused now)
#define OFF_LR16  (OFF_LC16 + (size_t)B_ * N_ * N_ / 2)         // bf16 L row-major
#define OFF_EPST  (OFF_LR16 + (size_t)B_ * N_ * N_ / 2)         // bf16 epsT[b][n][s]
#define OFF_EPSRM (OFF_EPST + (size_t)B_ * N_ * S_ / 2)         // bf16 eps[b][s][n] (& temp fp32 Lc)
#define OFF_LOSS  (OFF_EPSRM + (size_t)B_ * S_ * N_ / 2)        // uint loss keys, double-buffered
#define OFF_BAR   (OFF_LOSS + (size_t)2 * B_ * S_)              // int barrier counters

// ---------------- helpers ----------------
__device__ __forceinline__ float wred_f(float x) {
#pragma unroll
  for (int off = 32; off > 0; off >>= 1) x += __shfl_xor(x, off);
  return x;
}
__device__ __forceinline__ int wred_i(int x) {
#pragma unroll
  for (int off = 32; off > 0; off >>= 1) x += __shfl_xor(x, off);
  return x;
}
// monotone key: larger loss -> SMALLER key (top-K largest = K smallest keys)
__device__ __forceinline__ unsigned keyd(float x) {
  unsigned u = __float_as_uint(x);
  unsigned ku = (u & 0x80000000u) ? ~u : (u | 0x80000000u);
  return ~ku;
}
__device__ __forceinline__ uint16_t f2b(float f) {  // RNE fp32->bf16
  uint32_t u = __float_as_uint(f);
  uint32_t r = u + 0x7FFFu + ((u >> 16) & 1u);
  return (uint16_t)(r >> 16);
}
__device__ __forceinline__ float blo(uint32_t u) { return __uint_as_float(u << 16); }
__device__ __forceinline__ float bhi(uint32_t u) { return __uint_as_float(u & 0xFFFF0000u); }

// Michelot exact simplex projection (fixed point == reference sort formula); one wave.
__device__ __forceinline__ float michelot4(const float vp[4], float z) {
  bool act[4] = {true, true, true, true};
  float theta = 0.0f;
  int prev = -1;
  for (int pass = 0; pass < 300; ++pass) {
    float ls = 0.0f; int lc = 0;
#pragma unroll
    for (int j = 0; j < 4; ++j) { if (act[j]) { ls += vp[j]; lc += 1; } }
    ls = wred_f(ls);
    lc = wred_i(lc);
    theta = (ls - z) / (float)lc;
    if (lc == prev) break;
    prev = lc;
#pragma unroll
    for (int j = 0; j < 4; ++j) act[j] = (vp[j] > theta);
  }
  return theta;
}

__device__ __forceinline__ void proj_store(const float y[4], float fl_bil, float mass, float muf,
                                           const float* __restrict__ muB, int ln,
                                           float* w_s, float* c_sh) {
  float vp[4];
#pragma unroll
  for (int j = 0; j < 4; ++j) {
    const int n = 4 * ln + j;
    vp[j] = y[j] - ((n == BIL_) ? fl_bil : 0.0f);
  }
  const float theta = michelot4(vp, mass);
  const float4 m4 = *(const float4*)(muB + 4 * ln);
  const float mm[4] = {m4.x, m4.y, m4.z, m4.w};
  float wj[4];
  float cp = 0.0f;
#pragma unroll
  for (int j = 0; j < 4; ++j) {
    const int n = 4 * ln + j;
    wj[j] = fmaxf(vp[j] - theta, 0.0f) + ((n == BIL_) ? fl_bil : 0.0f);
    cp = fmaf(muf * mm[j], wj[j], cp);
  }
  cp = wred_f(cp);
  if (ln == 0) *c_sh = cp;
  *(float4*)(w_s + 4 * ln) = make_float4(wj[0], wj[1], wj[2], wj[3]);
}

// ---------------- Cholesky v3: one block (512 thr) per batch (proven r3) ----------------
__global__ __launch_bounds__(512) void chol_kernel(const float* __restrict__ sigma,
                                                   float* __restrict__ Lc) {
  const int b = blockIdx.x;
  const int tid = threadIdx.x;
  const int i = tid & 255;
  const int half = tid >> 8;
  const float* Sg = sigma + (size_t)b * N_ * N_;
  float* L = Lc + (size_t)b * N_ * N_;
  __shared__ __align__(16) float slab[248 * 8];
  __shared__ __align__(16) float spart[256][8];
  __shared__ __align__(16) float pnl[64];

  for (int j0 = 0; j0 < N_; j0 += 8) {
    for (int x = tid; x < j0 * 8; x += 512) {
      const int k = x >> 3, jj = x & 7;
      slab[x] = L[(size_t)k * N_ + (j0 + jj)];
    }
    float s[8];
    if (half == 0) {
#pragma unroll
      for (int jj = 0; jj < 8; ++jj) {
        float a = Sg[(size_t)(j0 + jj) * N_ + i];
        if (i == j0 + jj) a += JITTER_;
        s[jj] = a;
      }
    } else {
#pragma unroll
      for (int jj = 0; jj < 8; ++jj) s[jj] = 0.0f;
    }
    __syncthreads();

    const int kb = half ? (j0 >> 1) : 0;
    const int ke = half ? j0 : (j0 >> 1);
#pragma unroll 4
    for (int k = kb; k < ke; ++k) {
      const float lk = L[(size_t)k * N_ + i];
      const float4 h0 = *(const float4*)&slab[k * 8];
      const float4 h1 = *(const float4*)&slab[k * 8 + 4];
      s[0] = fmaf(-lk, h0.x, s[0]);
      s[1] = fmaf(-lk, h0.y, s[1]);
      s[2] = fmaf(-lk, h0.z, s[2]);
      s[3] = fmaf(-lk, h0.w, s[3]);
      s[4] = fmaf(-lk, h1.x, s[4]);
      s[5] = fmaf(-lk, h1.y, s[5]);
      s[6] = fmaf(-lk, h1.z, s[6]);
      s[7] = fmaf(-lk, h1.w, s[7]);
    }
    if (half == 1) {
      *(float4*)&spart[i][0] = make_float4(s[0], s[1], s[2], s[3]);
      *(float4*)&spart[i][4] = make_float4(s[4], s[5], s[6], s[7]);
    }
    __syncthreads();

    if (half == 0) {
      const float4 p0 = *(const float4*)&spart[i][0];
      const float4 p1 = *(const float4*)&spart[i][4];
      s[0] += p0.x; s[1] += p0.y; s[2] += p0.z; s[3] += p0.w;
      s[4] += p1.x; s[5] += p1.y; s[6] += p1.z; s[7] += p1.w;
      if ((i >> 3) == (j0 >> 3)) {
        const int base = j0 & 63;
        const int r = i & 7;
        float l[8], di[8];
#pragma unroll
        for (int m = 0; m < 8; ++m) {
          const float smv = __shfl(s[m], base + m);
          const float d = sqrtf(smv);
          const float dinv = 1.0f / d;
          di[m] = dinv;
          float lm;
          if (r == m) lm = d;
          else if (r > m) lm = s[m] * dinv;
          else lm = 0.0f;
          l[m] = lm;
#pragma unroll
          for (int mm = m + 1; mm < 8; ++mm) {
            s[mm] = fmaf(-lm, __shfl(lm, base + mm), s[mm]);
          }
        }
#pragma unroll
        for (int m = 0; m < 8; ++m) pnl[r * 8 + m] = (m < r) ? l[m] : ((m == r) ? di[r] : 0.0f);
#pragma unroll
        for (int m = 0; m < 8; ++m) L[(size_t)(j0 + m) * N_ + i] = l[m];
      }
    }
    __syncthreads();

    if (half == 0 && (i >> 3) != (j0 >> 3)) {
      float l[8];
      if (i > j0) {
#pragma unroll
        for (int m = 0; m < 8; ++m) {
          float sm = s[m];
#pragma unroll
          for (int mm = 0; mm < 8; ++mm) {
            if (mm < m) sm = fmaf(-l[mm], pnl[m * 8 + mm], sm);
          }
          l[m] = sm * pnl[m * 8 + m];
        }
      } else {
#pragma unroll
        for (int m = 0; m < 8; ++m) l[m] = 0.0f;
      }
#pragma unroll
      for (int m = 0; m < 8; ++m) L[(size_t)(j0 + m) * N_ + i] = l[m];
    }
    __syncthreads();
  }
}

// ---------------- pack L (row-major bf16 only; col-major copy no longer needed) ----------------
__global__ __launch_bounds__(256) void lpack_kernel(const float* __restrict__ Lc,
                                                    uint16_t* __restrict__ Lr16) {
  const int b = blockIdx.x;
  const float* Lp = Lc + (size_t)b * N_ * N_;
  uint16_t* R16 = Lr16 + (size_t)b * N_ * N_;
  __shared__ float tl[32][33];
  const int tx = threadIdx.x & 31;
  const int ty = threadIdx.x >> 5;
  for (int kt = 0; kt < 8; ++kt) {
    for (int it = 0; it < 8; ++it) {
#pragma unroll
      for (int rr = 0; rr < 4; ++rr) {
        const int k = kt * 32 + ty + 8 * rr;
        const int ii = it * 32 + tx;
        tl[ty + 8 * rr][tx] = Lp[(size_t)k * N_ + ii];
      }
      __syncthreads();
#pragma unroll
      for (int rr = 0; rr < 4; ++rr) {
        const int ii = it * 32 + ty + 8 * rr;
        const int k = kt * 32 + tx;
        R16[(size_t)ii * N_ + k] = f2b(tl[tx][ty + 8 * rr]);
      }
      __syncthreads();
    }
  }
}

// ---------------- eps -> bf16 both layouts; zero bar ----------------
__global__ __launch_bounds__(256) void etrans_kernel(const float* __restrict__ eps,
                                                     uint16_t* __restrict__ epsT16,
                                                     uint16_t* __restrict__ epsrm16,
                                                     int* __restrict__ bar) {
  const int b = blockIdx.x;
  const int s0 = blockIdx.y * 50;
  const int t = threadIdx.x;
  if (blockIdx.x == 0 && blockIdx.y == 0 && t < 64) bar[t] = 0;
  __shared__ float tl[50][257];
  const float* E = eps + ((size_t)b * S_ + s0) * N_;
  for (int p = 0; p < 50; ++p) tl[p][t] = E[(size_t)p * N_ + t];
  __syncthreads();
  uint16_t* RM = epsrm16 + ((size_t)b * S_ + s0) * N_;
  for (int p = 0; p < 50; ++p) RM[(size_t)p * N_ + t] = f2b(tl[p][t]);
  uint16_t* ET = epsT16 + (size_t)b * N_ * S_;
  const int g = t / 50, ss = t % 50;
  if (g < 5) {
    for (int q = 0; q < 52; ++q) {
      const int n = q * 5 + g;
      if (n < N_) ET[(size_t)n * S_ + s0 + ss] = f2b(tl[ss][n]);
    }
  }
}

// ---------------- solver: 4 blocks (1024 thr) per batch, grid 256, 1 block/CU ----------------
// r9: r7 structure + iteration-invariant data hoisted out of the loop:
//   - eps stage-1 slice lives in 64 persistent VGPRs per thread (loaded once, reused 200x)
//   - L lives in LDS as ONE padded row-major u32 image [256][129] (129%32==1 -> both row- and
//     column-parallel access patterns are bank-conflict-free), serving BOTH matvecs.
// Per-iter global traffic is now only e-pass rows + key publish/gather.
// NO launch_bounds waves arg: 1024-thr block alone caps VGPR at 128 (r8 lesson: pinning -> spills).
__global__ __launch_bounds__(1024) void solve_kernel(
    const float* __restrict__ mu, const int* __restrict__ pcrisis,
    const int* __restrict__ plam, const uint16_t* __restrict__ Lr16,
    const uint16_t* __restrict__ epsT16, const uint16_t* __restrict__ epsrm16,
    unsigned* __restrict__ lossbits, int* __restrict__ bar, float* __restrict__ out) {
  const int bx = blockIdx.x;
  const int b = bx & (B_ - 1);
  const int part = bx >> 6;  // 0..3; blocks b+64k land on XCD b%8 under %8 RR
  const int t = threadIdx.x;
  const int ln = t & 63;
  const int s0 = part * SCH_;

  __shared__ __align__(16) uint32_t Lsh[256 * 129];  // padded L image (132 KB)
  __shared__ __align__(16) float w_s[N_];
  __shared__ __align__(16) float v_s[N_];
  __shared__ __align__(16) float scratch[8][N_];  // matvec/stage1/e partials (flat-aliased)
  __shared__ __align__(16) uint16_t lists[S_];
  __shared__ __align__(16) int hist[4][256];      // one bank per radix pass
  __shared__ float c_sh;
  __shared__ int lcnt;
  __shared__ float sum_sh;

  const int crisis = pcrisis[0];
  const int lamv = plam[0];
  const float muf = 1.0f + ((lamv > 0) ? (1.0f / fmaxf((float)lamv, 0.1f)) : 0.0f);
  const float fl_bil = SAFETY_ * (float)crisis;
  const float mass = 1.0f - fl_bil;

  const uint16_t* LrB = Lr16 + (size_t)b * N_ * N_;
  const float* muB = mu + (size_t)b * N_;
  const uint16_t* epsTB = epsT16 + (size_t)b * N_ * S_;
  const uint16_t* epsRB = epsrm16 + (size_t)b * S_ * N_;
  float* sc1 = &scratch[0][0];

  // ---- stage L into LDS: Lsh[i*129 + kp] = Lr16 u32 image [i*128 + kp] ----
  {
    const uint32_t* Lg = (const uint32_t*)LrB;
    for (int x = t; x < 256 * 128; x += 1024) Lsh[x + (x >> 7)] = Lg[x];
  }

  // ---- eps slice -> 64 persistent VGPRs per thread (iteration-invariant) ----
  uint32_t er[64];
  {
    const int q = t >> 8;     // n-quarter (64 n)
    const int idx = t & 255;  // scenario-pair
    if (idx < SCH_ / 2) {
      const uint32_t* col = (const uint32_t*)(epsTB + (size_t)(64 * q) * S_) + (s0 / 2 + idx);
#pragma unroll
      for (int j = 0; j < 64; ++j) er[j] = col[(size_t)j * (S_ / 2)];
    } else {
#pragma unroll
      for (int j = 0; j < 64; ++j) er[j] = 0u;
    }
  }

  // ---- w0 = proj(uniform) ----
  if (t < 64) {
    float y[4];
#pragma unroll
    for (int j = 0; j < 4; ++j) y[j] = 1.0f / (float)N_;
    proj_store(y, fl_bil, mass, muf, muB, ln, w_s, &c_sh);
  }
  __syncthreads();  // B1 (covers Lsh staging + w0)

  for (int it = 0; it < NITER_; ++it) {
    // ---- v = L^T w partials: 8 i-octants x 128 k-pairs (LDS-resident L) ----
    {
      const int oct = t >> 7, kp = t & 127;
      const int i0 = 32 * oct;
      float a0 = 0.0f, a1 = 0.0f;
#pragma unroll 4
      for (int ii = 0; ii < 32; ++ii) {
        const uint32_t u = Lsh[(size_t)(i0 + ii) * 129 + kp];
        const float ww = w_s[i0 + ii];
        a0 = fmaf(blo(u), ww, a0);
        a1 = fmaf(bhi(u), ww, a1);
      }
      *(float2*)&scratch[oct][2 * kp] = make_float2(a0, a1);
    }
    __syncthreads();  // B2

    // ---- v-reduce (t<256) + zero hist banks & lcnt (t>=256) ----
    if (t < N_) {
      v_s[t] = ((scratch[0][t] + scratch[1][t]) + (scratch[2][t] + scratch[3][t])) +
               ((scratch[4][t] + scratch[5][t]) + (scratch[6][t] + scratch[7][t]));
    } else {
      for (int x = t - 256; x < 4 * 256; x += 768) ((int*)hist)[x] = 0;
      if (t == 256) lcnt = 0;
    }
    __syncthreads();  // B3

    // ---- stage 1: partial losses from REGISTER eps (4 n-quarters x 250 pairs) ----
    const float cc = c_sh;
    {
      const int q = t >> 8;
      const int idx = t & 255;
      if (idx < SCH_ / 2) {
        float a0 = 0.0f, a1 = 0.0f;
#pragma unroll
        for (int j = 0; j < 64; ++j) {
          const float vv = v_s[64 * q + j];
          a0 = fmaf(blo(er[j]), vv, a0);
          a1 = fmaf(bhi(er[j]), vv, a1);
        }
        *(float2*)&sc1[q * SCH_ + 2 * idx] = make_float2(a0, a1);
      }
    }
    __syncthreads();  // B4

    // ---- combine + publish keys (relaxed agent atomics) ----
    unsigned* lgbuf = lossbits + ((it & 1) ? (size_t)B_ * S_ : 0) + (size_t)b * S_;
    if (t < SCH_) {
      const float lv = -(cc + ((sc1[t] + sc1[SCH_ + t]) + (sc1[2 * SCH_ + t] + sc1[3 * SCH_ + t])));
      __hip_atomic_store(&lgbuf[s0 + t], keyd(lv), __ATOMIC_RELAXED, __HIP_MEMORY_SCOPE_AGENT);
    }
    __syncthreads();  // B5 (drains vmcnt before barrier exit)

    // ---- per-batch spin barrier ----
    if (t == 0) {
      __hip_atomic_fetch_add(&bar[b], 1, __ATOMIC_RELAXED, __HIP_MEMORY_SCOPE_AGENT);
      const int target = PART_ * (it + 1);
      while (__hip_atomic_load(&bar[b], __ATOMIC_RELAXED, __HIP_MEMORY_SCOPE_AGENT) < target) {
        __builtin_amdgcn_s_sleep(1);
      }
    }
    __syncthreads();  // B6

    // ---- gather all 2000 keys into registers (thread t owns scenarios 2t, 2t+1) + pass-0 hist ----
    uint32_t kx = 0xFFFFFFFFu, ky = 0xFFFFFFFFu;
    if (t < S_ / 2) {
      const unsigned long long two = __hip_atomic_load(
          (const unsigned long long*)(lgbuf + 2 * t), __ATOMIC_RELAXED, __HIP_MEMORY_SCOPE_AGENT);
      kx = (uint32_t)two;
      ky = (uint32_t)(two >> 32);
      atomicAdd(&hist[0][kx >> 24], 1);
      atomicAdd(&hist[0][ky >> 24], 1);
    }
    __syncthreads();  // B7

    // ---- 4-pass radix select: redundant all-wave scan (no publish barrier) ----
    unsigned pref = 0;
    int r = K_;
#pragma unroll
    for (int pass = 0; pass < 4; ++pass) {
      const int shift = 24 - 8 * pass;
      // redundant scan of hist[pass] by every wave
      {
        const int4 c4 = *(const int4*)&hist[pass][4 * ln];
        const int c0 = c4.x, c1 = c4.y, c2 = c4.z, c3 = c4.w;
        const int tot = c0 + c1 + c2 + c3;
        int sc = tot;
#pragma unroll
        for (int off = 1; off < 64; off <<= 1) {
          const int o = __shfl_up(sc, off);
          if (ln >= off) sc += o;
        }
        const int excl = sc - tot;
        const bool has = (excl < r) && (r <= sc);
        const unsigned long long bal = __ballot(has);
        const int lstar = __ffsll(bal) - 1;
        const int bc0 = __shfl(c0, lstar);
        const int bc1 = __shfl(c1, lstar);
        const int bc2 = __shfl(c2, lstar);
        const int bexcl = __shfl(excl, lstar);
        const int rr = r - bexcl;
        int d, rn;
        if (rr <= bc0) { d = 0; rn = rr; }
        else if (rr <= bc0 + bc1) { d = 1; rn = rr - bc0; }
        else if (rr <= bc0 + bc1 + bc2) { d = 2; rn = rr - bc0 - bc1; }
        else { d = 3; rn = rr - bc0 - bc1 - bc2; }
        pref |= (unsigned)(4 * lstar + d) << shift;
        r = rn;
      }
      if (pass < 3) {
        // next-pass histogram over prefix-matching keys (registers)
        const unsigned msk = 0xFFFFFFFFu << shift;
        const int nshift = shift - 8;
        if (t < S_ / 2) {
          if ((kx & msk) == pref) atomicAdd(&hist[pass + 1][(kx >> nshift) & 255], 1);
          if ((ky & msk) == pref) atomicAdd(&hist[pass + 1][(ky >> nshift) & 255], 1);
        }
      } else {
        // compact: selected = key <= pref (== loss >= K-th largest loss)
        if (t < S_ / 2) {
          if (kx <= pref) { const int p = atomicAdd(&lcnt, 1); lists[p] = (uint16_t)(2 * t); }
          if (ky <= pref) { const int p = atomicAdd(&lcnt, 1); lists[p] = (uint16_t)(2 * t + 1); }
        }
      }
      __syncthreads();  // B8..B11
    }

    const int cnt = lcnt;
    const float weight = 1.0f / (float)((cnt > K_) ? cnt : K_);

    // ---- e partials: 8 row-groups x 128 n-pairs (global epsRB; ~cnt rows) ----
    {
      const int rt = t >> 7;
      const int np = t & 127;
      float a0 = 0.0f, a1 = 0.0f;
      for (int p = rt; p < cnt; p += 8) {
        const uint32_t u = *((const uint32_t*)(epsRB + (size_t)lists[p] * N_) + np);
        a0 += blo(u);
        a1 += bhi(u);
      }
      *(float2*)&scratch[rt][2 * np] = make_float2(a0, a1);
    }
    __syncthreads();  // B12

    // ---- e-reduce (wave 0): stash e in v_s ----
    if (t < 64) {
      float4 acc = make_float4(0.0f, 0.0f, 0.0f, 0.0f);
#pragma unroll
      for (int oct = 0; oct < 8; ++oct) {
        const float4 x = *(const float4*)&scratch[oct][4 * ln];
        acc.x += x.x; acc.y += x.y; acc.z += x.z; acc.w += x.w;
      }
      *(float4*)&v_s[4 * ln] = acc;
    }
    __syncthreads();  // B12b: e ready in v_s

    // ---- u = L e partials: 4 k-groups x 256 i (LDS-resident L, row access) ----
    {
      const int g = t >> 8;     // k-group (64 k = 32 u32)
      const int i = t & 255;
      const int kp0 = 32 * g;
      float a = 0.0f;
#pragma unroll 4
      for (int kk = 0; kk < 32; ++kk) {
        const uint32_t u = Lsh[(size_t)i * 129 + kp0 + kk];
        const float2 e2 = *(const float2*)&v_s[2 * (kp0 + kk)];
        a = fmaf(blo(u), e2.x, a);
        a = fmaf(bhi(u), e2.y, a);
      }
      scratch[g][i] = a;
    }
    __syncthreads();  // B13

    // ---- w update + projection (wave 0), u-reduce (4 partials) fused ----
    if (t < 64) {
      float4 u4 = make_float4(0.0f, 0.0f, 0.0f, 0.0f);
#pragma unroll
      for (int g = 0; g < 4; ++g) {
        const float4 x = *(const float4*)&scratch[g][4 * ln];
        u4.x += x.x; u4.y += x.y; u4.z += x.z; u4.w += x.w;
      }
      const float lr = 0.5f / sqrtf((float)it + 1.0f);
      const float4 w4 = *(const float4*)(w_s + 4 * ln);
      const float4 m4 = *(const float4*)(muB + 4 * ln);
      float y[4];
      y[0] = w4.x + lr * (muf * m4.x + u4.x * weight);
      y[1] = w4.y + lr * (muf * m4.y + u4.y * weight);
      y[2] = w4.z + lr * (muf * m4.z + u4.z * weight);
      y[3] = w4.w + lr * (muf * m4.w + u4.w * weight);
      proj_store(y, fl_bil, mass, muf, muB, ln, w_s, &c_sh);
    }
    __syncthreads();  // B14 (doubles as next iteration's B1)
  }

  // ---- output (part 0 only): w / (sum + 1e-8) ----
  if (part == 0) {
    if (t < 64) {
      const float4 w4 = *(const float4*)(w_s + 4 * ln);
      const float ssum = wred_f(w4.x + w4.y + w4.z + w4.w);
      if (ln == 0) sum_sh = ssum;
    }
    __syncthreads();
    if (t < N_) out[(size_t)b * N_ + t] = fmaxf(w_s[t], 0.0f) / (sum_sh + 1e-8f);
  }
}

extern "C" void kernel_launch(void* const* d_in, const int* in_sizes, int n_in,
                              void* d_out, int out_size, void* d_ws, size_t ws_size,
                              hipStream_t stream) {
  const float* mu = (const float*)d_in[0];
  const float* sigma = (const float*)d_in[1];
  const float* eps = (const float*)d_in[2];
  const int* crisis = (const int*)d_in[3];
  const int* lam = (const int*)d_in[4];
  float* out = (float*)d_out;
  float* ws = (float*)d_ws;

  uint16_t* Lr16 = (uint16_t*)(ws + OFF_LR16);
  uint16_t* epsT16 = (uint16_t*)(ws + OFF_EPST);
  uint16_t* epsrm16 = (uint16_t*)(ws + OFF_EPSRM);
  float* Lc = ws + OFF_EPSRM;  // fp32 L aliases epsrm16 (dead before etrans writes it)
  unsigned* lossbits = (unsigned*)(ws + OFF_LOSS);
  int* bar = (int*)(ws + OFF_BAR);

  chol_kernel<<<dim3(B_), dim3(512), 0, stream>>>(sigma, Lc);
  lpack_kernel<<<dim3(B_), dim3(256), 0, stream>>>(Lc, Lr16);
  etrans_kernel<<<dim3(B_, S_ / 50), dim3(256), 0, stream>>>(eps, epsT16, epsrm16, bar);

  solve_kernel<<<dim3(PART_ * B_), dim3(1024), 0, stream>>>(
      mu, crisis, lam, Lr16, epsT16, epsrm16, lossbits, bar, out);
}

// Round 3
// 5103.078 us; speedup vs baseline: 1.9825x; 1.1194x over previous
//
#include <hip/hip_runtime.h>
#include <stdint.h>

#define B_   64
#define N_   256
#define S_   2000
#define K_   100
#define BIL_ 4
#define NITER_ 200
#define JITTER_ 1e-4f
#define SAFETY_ 0.5f
#define PART_ 4
#define SCH_  (S_ / PART_)   // 500 scenarios per block
#define GS_   50             // scenarios per g_kernel block

// ---- ws layout (offsets in float units) ----
#define OFF_LC16  ((size_t)0)                                   // (unused)
#define OFF_LR16  (OFF_LC16 + (size_t)B_ * N_ * N_ / 2)         // bf16 L row-major
#define OFF_GT    (OFF_LR16 + (size_t)B_ * N_ * N_ / 2)         // bf16 G^T [b][m][s]
#define OFF_GR    (OFF_GT + (size_t)B_ * N_ * S_ / 2)           // bf16 G [b][s][m] (& temp fp32 Lc)
#define OFF_LOSS  (OFF_GR + (size_t)B_ * S_ * N_ / 2)           // uint loss keys, double-buffered
#define OFF_BAR   (OFF_LOSS + (size_t)2 * B_ * S_)              // int barrier counters

// ---------------- helpers ----------------
__device__ __forceinline__ float wred_f(float x) {
#pragma unroll
  for (int off = 32; off > 0; off >>= 1) x += __shfl_xor(x, off);
  return x;
}
__device__ __forceinline__ int wred_i(int x) {
#pragma unroll
  for (int off = 32; off > 0; off >>= 1) x += __shfl_xor(x, off);
  return x;
}
// monotone key: larger loss -> SMALLER key (top-K largest = K smallest keys)
__device__ __forceinline__ unsigned keyd(float x) {
  unsigned u = __float_as_uint(x);
  unsigned ku = (u & 0x80000000u) ? ~u : (u | 0x80000000u);
  return ~ku;
}
__device__ __forceinline__ uint16_t f2b(float f) {  // RNE fp32->bf16
  uint32_t u = __float_as_uint(f);
  uint32_t r = u + 0x7FFFu + ((u >> 16) & 1u);
  return (uint16_t)(r >> 16);
}
__device__ __forceinline__ float blo(uint32_t u) { return __uint_as_float(u << 16); }
__device__ __forceinline__ float bhi(uint32_t u) { return __uint_as_float(u & 0xFFFF0000u); }

// Michelot exact simplex projection (fixed point == reference sort formula); one wave.
__device__ __forceinline__ float michelot4(const float vp[4], float z) {
  bool act[4] = {true, true, true, true};
  float theta = 0.0f;
  int prev = -1;
  for (int pass = 0; pass < 300; ++pass) {
    float ls = 0.0f; int lc = 0;
#pragma unroll
    for (int j = 0; j < 4; ++j) { if (act[j]) { ls += vp[j]; lc += 1; } }
    ls = wred_f(ls);
    lc = wred_i(lc);
    theta = (ls - z) / (float)lc;
    if (lc == prev) break;
    prev = lc;
#pragma unroll
    for (int j = 0; j < 4; ++j) act[j] = (vp[j] > theta);
  }
  return theta;
}

__device__ __forceinline__ void proj_store(const float y[4], float fl_bil, float mass, float muf,
                                           const float* __restrict__ muB, int ln,
                                           float* w_s, float* c_sh) {
  float vp[4];
#pragma unroll
  for (int j = 0; j < 4; ++j) {
    const int n = 4 * ln + j;
    vp[j] = y[j] - ((n == BIL_) ? fl_bil : 0.0f);
  }
  const float theta = michelot4(vp, mass);
  const float4 m4 = *(const float4*)(muB + 4 * ln);
  const float mm[4] = {m4.x, m4.y, m4.z, m4.w};
  float wj[4];
  float cp = 0.0f;
#pragma unroll
  for (int j = 0; j < 4; ++j) {
    const int n = 4 * ln + j;
    wj[j] = fmaxf(vp[j] - theta, 0.0f) + ((n == BIL_) ? fl_bil : 0.0f);
    cp = fmaf(muf * mm[j], wj[j], cp);
  }
  cp = wred_f(cp);
  if (ln == 0) *c_sh = cp;
  *(float4*)(w_s + 4 * ln) = make_float4(wj[0], wj[1], wj[2], wj[3]);
}

// ---------------- Cholesky v3: one block (512 thr) per batch (proven r3) ----------------
__global__ __launch_bounds__(512) void chol_kernel(const float* __restrict__ sigma,
                                                   float* __restrict__ Lc) {
  const int b = blockIdx.x;
  const int tid = threadIdx.x;
  const int i = tid & 255;
  const int half = tid >> 8;
  const float* Sg = sigma + (size_t)b * N_ * N_;
  float* L = Lc + (size_t)b * N_ * N_;
  __shared__ __align__(16) float slab[248 * 8];
  __shared__ __align__(16) float spart[256][8];
  __shared__ __align__(16) float pnl[64];

  for (int j0 = 0; j0 < N_; j0 += 8) {
    for (int x = tid; x < j0 * 8; x += 512) {
      const int k = x >> 3, jj = x & 7;
      slab[x] = L[(size_t)k * N_ + (j0 + jj)];
    }
    float s[8];
    if (half == 0) {
#pragma unroll
      for (int jj = 0; jj < 8; ++jj) {
        float a = Sg[(size_t)(j0 + jj) * N_ + i];
        if (i == j0 + jj) a += JITTER_;
        s[jj] = a;
      }
    } else {
#pragma unroll
      for (int jj = 0; jj < 8; ++jj) s[jj] = 0.0f;
    }
    __syncthreads();

    const int kb = half ? (j0 >> 1) : 0;
    const int ke = half ? j0 : (j0 >> 1);
#pragma unroll 4
    for (int k = kb; k < ke; ++k) {
      const float lk = L[(size_t)k * N_ + i];
      const float4 h0 = *(const float4*)&slab[k * 8];
      const float4 h1 = *(const float4*)&slab[k * 8 + 4];
      s[0] = fmaf(-lk, h0.x, s[0]);
      s[1] = fmaf(-lk, h0.y, s[1]);
      s[2] = fmaf(-lk, h0.z, s[2]);
      s[3] = fmaf(-lk, h0.w, s[3]);
      s[4] = fmaf(-lk, h1.x, s[4]);
      s[5] = fmaf(-lk, h1.y, s[5]);
      s[6] = fmaf(-lk, h1.z, s[6]);
      s[7] = fmaf(-lk, h1.w, s[7]);
    }
    if (half == 1) {
      *(float4*)&spart[i][0] = make_float4(s[0], s[1], s[2], s[3]);
      *(float4*)&spart[i][4] = make_float4(s[4], s[5], s[6], s[7]);
    }
    __syncthreads();

    if (half == 0) {
      const float4 p0 = *(const float4*)&spart[i][0];
      const float4 p1 = *(const float4*)&spart[i][4];
      s[0] += p0.x; s[1] += p0.y; s[2] += p0.z; s[3] += p0.w;
      s[4] += p1.x; s[5] += p1.y; s[6] += p1.z; s[7] += p1.w;
      if ((i >> 3) == (j0 >> 3)) {
        const int base = j0 & 63;
        const int r = i & 7;
        float l[8], di[8];
#pragma unroll
        for (int m = 0; m < 8; ++m) {
          const float smv = __shfl(s[m], base + m);
          const float d = sqrtf(smv);
          const float dinv = 1.0f / d;
          di[m] = dinv;
          float lm;
          if (r == m) lm = d;
          else if (r > m) lm = s[m] * dinv;
          else lm = 0.0f;
          l[m] = lm;
#pragma unroll
          for (int mm = m + 1; mm < 8; ++mm) {
            s[mm] = fmaf(-lm, __shfl(lm, base + mm), s[mm]);
          }
        }
#pragma unroll
        for (int m = 0; m < 8; ++m) pnl[r * 8 + m] = (m < r) ? l[m] : ((m == r) ? di[r] : 0.0f);
#pragma unroll
        for (int m = 0; m < 8; ++m) L[(size_t)(j0 + m) * N_ + i] = l[m];
      }
    }
    __syncthreads();

    if (half == 0 && (i >> 3) != (j0 >> 3)) {
      float l[8];
      if (i > j0) {
#pragma unroll
        for (int m = 0; m < 8; ++m) {
          float sm = s[m];
#pragma unroll
          for (int mm = 0; mm < 8; ++mm) {
            if (mm < m) sm = fmaf(-l[mm], pnl[m * 8 + mm], sm);
          }
          l[m] = sm * pnl[m * 8 + m];
        }
      } else {
#pragma unroll
        for (int m = 0; m < 8; ++m) l[m] = 0.0f;
      }
#pragma unroll
      for (int m = 0; m < 8; ++m) L[(size_t)(j0 + m) * N_ + i] = l[m];
    }
    __syncthreads();
  }
}

// ---------------- pack L (row-major bf16: Lr16[i*N+k] = L[i][k]) ----------------
__global__ __launch_bounds__(256) void lpack_kernel(const float* __restrict__ Lc,
                                                    uint16_t* __restrict__ Lr16) {
  const int b = blockIdx.x;
  const float* Lp = Lc + (size_t)b * N_ * N_;
  uint16_t* R16 = Lr16 + (size_t)b * N_ * N_;
  __shared__ float tl[32][33];
  const int tx = threadIdx.x & 31;
  const int ty = threadIdx.x >> 5;
  for (int kt = 0; kt < 8; ++kt) {
    for (int it = 0; it < 8; ++it) {
#pragma unroll
      for (int rr = 0; rr < 4; ++rr) {
        const int k = kt * 32 + ty + 8 * rr;
        const int ii = it * 32 + tx;
        tl[ty + 8 * rr][tx] = Lp[(size_t)k * N_ + ii];
      }
      __syncthreads();
#pragma unroll
      for (int rr = 0; rr < 4; ++rr) {
        const int ii = it * 32 + ty + 8 * rr;
        const int k = kt * 32 + tx;
        R16[(size_t)ii * N_ + k] = f2b(tl[tx][ty + 8 * rr]);
      }
      __syncthreads();
    }
  }
}

// ---------------- G = eps @ L^T (one-time GEMM, lower-tri aware); zero bar ----------------
// G[s][m] = sum_n L[m][n] * eps[s][n]  (= R without mu). Thread t = asset m, 50 scenarios.
// eps tile bf16 in LDS (broadcast reads); L row streamed from L2 (bound by lower-tri: n <= m).
__global__ __launch_bounds__(256) void g_kernel(const float* __restrict__ eps,
                                                const uint16_t* __restrict__ Lr16,
                                                uint16_t* __restrict__ GT16,
                                                uint16_t* __restrict__ GR16,
                                                int* __restrict__ bar) {
  const int b = blockIdx.x;
  const int s0 = blockIdx.y * GS_;
  const int t = threadIdx.x;
  if (b == 0 && blockIdx.y == 0 && t < 64) bar[t] = 0;
  __shared__ __align__(16) uint16_t esh[GS_][N_];  // bf16 eps tile [s][n]
  const float* E = eps + ((size_t)b * S_ + s0) * N_;
  for (int p = 0; p < GS_; ++p) esh[p][t] = f2b(E[(size_t)p * N_ + t]);
  __syncthreads();

  const uint32_t* Lrow = (const uint32_t*)(Lr16 + (size_t)b * N_ * N_) + (size_t)t * (N_ / 2);
  float acc[GS_];
#pragma unroll
  for (int s = 0; s < GS_; ++s) acc[s] = 0.0f;
  const int jmax = (t >> 1) + 1;  // L[m][n] == 0 for n > m
  for (int j = 0; j < jmax; ++j) {
    const uint32_t lu = Lrow[j];
    const float l0 = blo(lu), l1 = bhi(lu);
#pragma unroll
    for (int s = 0; s < GS_; ++s) {
      const uint32_t eu = *(const uint32_t*)&esh[s][2 * j];
      acc[s] = fmaf(l1, bhi(eu), fmaf(l0, blo(eu), acc[s]));
    }
  }
  // GR[s][m]: coalesced across threads
  uint16_t* GRb = GR16 + ((size_t)b * S_ + s0) * N_ + t;
  for (int s = 0; s < GS_; ++s) GRb[(size_t)s * N_] = f2b(acc[s]);
  // GT[m][s]: 25 contiguous u32 per thread (s-pairs packed)
  uint32_t* GTb = (uint32_t*)(GT16 + (size_t)b * N_ * S_ + (size_t)t * S_ + s0);
#pragma unroll
  for (int u = 0; u < GS_ / 2; ++u) {
    const uint32_t pk = (uint32_t)f2b(acc[2 * u]) | ((uint32_t)f2b(acc[2 * u + 1]) << 16);
    GTb[u] = pk;
  }
}

// ---------------- solver: 4 blocks (1024 thr) per batch, grid 256, 1 block/CU ----------------
// r10: G-form. loss_s = -(c + G_s . w); u = sum over selected rows of G. The per-iter L^T w
// matvec, v-reduce, e-pass and L e matvec are gone (folded into the one-time G GEMM).
// Per-thread G slice (64 u32) preloaded into VGPRs; launch_bounds(1024,4) -> 128-VGPR budget
// (r9 lesson: default budget 64 demotes the array; r8 lesson: never pin below need).
__global__ __launch_bounds__(1024, 4) void solve_kernel(
    const float* __restrict__ mu, const int* __restrict__ pcrisis,
    const int* __restrict__ plam, const uint16_t* __restrict__ GT16,
    const uint16_t* __restrict__ GR16, unsigned* __restrict__ lossbits,
    int* __restrict__ bar, float* __restrict__ out) {
  const int bx = blockIdx.x;
  const int b = bx & (B_ - 1);
  const int part = bx >> 6;  // 0..3; blocks b+64k land on XCD b%8 under %8 RR
  const int t = threadIdx.x;
  const int ln = t & 63;
  const int s0 = part * SCH_;

  __shared__ __align__(16) float w_s[N_];
  __shared__ __align__(16) float scratch[8][N_];  // loss partials (flat) / usum partials
  __shared__ __align__(16) uint16_t lists[S_];
  __shared__ __align__(16) int hist[4][256];      // one bank per radix pass
  __shared__ float c_sh;
  __shared__ int lcnt;
  __shared__ float sum_sh;

  const int crisis = pcrisis[0];
  const int lamv = plam[0];
  const float muf = 1.0f + ((lamv > 0) ? (1.0f / fmaxf((float)lamv, 0.1f)) : 0.0f);
  const float fl_bil = SAFETY_ * (float)crisis;
  const float mass = 1.0f - fl_bil;

  const float* muB = mu + (size_t)b * N_;
  const uint32_t* GTB = (const uint32_t*)(GT16 + (size_t)b * N_ * S_);
  const uint32_t* GRB = (const uint32_t*)(GR16 + (size_t)b * S_ * N_);
  float* sc1 = &scratch[0][0];

  // ---- preload my G slice: scenario-pair idx, m-quarter q -> 64 u32 in VGPRs ----
  const int q = t >> 8;     // m-quarter (64 m)
  const int idx = t & 255;  // scenario-pair (idx < 250 active)
  uint32_t gr[64];
  {
    const uint32_t* col = GTB + (size_t)(64 * q) * (S_ / 2) + (s0 >> 1) + idx;
    if (idx < SCH_ / 2) {
#pragma unroll
      for (int j = 0; j < 64; ++j) gr[j] = col[(size_t)j * (S_ / 2)];
    } else {
#pragma unroll
      for (int j = 0; j < 64; ++j) gr[j] = 0u;
    }
  }

  // ---- w0 = proj(uniform) ----
  if (t < 64) {
    float y[4];
#pragma unroll
    for (int j = 0; j < 4; ++j) y[j] = 1.0f / (float)N_;
    proj_store(y, fl_bil, mass, muf, muB, ln, w_s, &c_sh);
  }
  __syncthreads();  // B1

  for (int it = 0; it < NITER_; ++it) {
    // ---- loss partials from register G: a = G_s[64q..64q+63] . w ----
    if (idx < SCH_ / 2) {
      float a0 = 0.0f, a1 = 0.0f;
#pragma unroll
      for (int j = 0; j < 64; ++j) {
        const float ww = w_s[64 * q + j];  // broadcast
        a0 = fmaf(blo(gr[j]), ww, a0);
        a1 = fmaf(bhi(gr[j]), ww, a1);
      }
      *(float2*)&sc1[q * SCH_ + 2 * idx] = make_float2(a0, a1);
    }
    __syncthreads();  // B2

    // ---- combine + publish keys (t<500); zero hist banks & lcnt (t>=512) ----
    unsigned* lgbuf = lossbits + ((it & 1) ? (size_t)B_ * S_ : 0) + (size_t)b * S_;
    if (t < SCH_) {
      const float lv = -(c_sh + ((sc1[t] + sc1[SCH_ + t]) + (sc1[2 * SCH_ + t] + sc1[3 * SCH_ + t])));
      __hip_atomic_store(&lgbuf[s0 + t], keyd(lv), __ATOMIC_RELAXED, __HIP_MEMORY_SCOPE_AGENT);
    } else if (t >= 512) {
      for (int x = t - 512; x < 4 * 256; x += 512) ((int*)hist)[x] = 0;
      if (t == 512) lcnt = 0;
    }
    __syncthreads();  // B3 (drains vmcnt before barrier exit)

    // ---- per-batch spin barrier ----
    if (t == 0) {
      __hip_atomic_fetch_add(&bar[b], 1, __ATOMIC_RELAXED, __HIP_MEMORY_SCOPE_AGENT);
      const int target = PART_ * (it + 1);
      while (__hip_atomic_load(&bar[b], __ATOMIC_RELAXED, __HIP_MEMORY_SCOPE_AGENT) < target) {
        __builtin_amdgcn_s_sleep(1);
      }
    }
    __syncthreads();  // B4

    // ---- gather all 2000 keys (thread t owns scenarios 2t, 2t+1) + pass-0 hist ----
    uint32_t kx = 0xFFFFFFFFu, ky = 0xFFFFFFFFu;
    if (t < S_ / 2) {
      const unsigned long long two = __hip_atomic_load(
          (const unsigned long long*)(lgbuf + 2 * t), __ATOMIC_RELAXED, __HIP_MEMORY_SCOPE_AGENT);
      kx = (uint32_t)two;
      ky = (uint32_t)(two >> 32);
      atomicAdd(&hist[0][kx >> 24], 1);
      atomicAdd(&hist[0][ky >> 24], 1);
    }
    __syncthreads();  // B5

    // ---- 4-pass radix select: redundant all-wave scan ----
    unsigned pref = 0;
    int r = K_;
#pragma unroll
    for (int pass = 0; pass < 4; ++pass) {
      const int shift = 24 - 8 * pass;
      {
        const int4 c4 = *(const int4*)&hist[pass][4 * ln];
        const int c0 = c4.x, c1 = c4.y, c2 = c4.z, c3 = c4.w;
        const int tot = c0 + c1 + c2 + c3;
        int sc = tot;
#pragma unroll
        for (int off = 1; off < 64; off <<= 1) {
          const int o = __shfl_up(sc, off);
          if (ln >= off) sc += o;
        }
        const int excl = sc - tot;
        const bool has = (excl < r) && (r <= sc);
        const unsigned long long bal = __ballot(has);
        const int lstar = __ffsll(bal) - 1;
        const int bc0 = __shfl(c0, lstar);
        const int bc1 = __shfl(c1, lstar);
        const int bc2 = __shfl(c2, lstar);
        const int bexcl = __shfl(excl, lstar);
        const int rr = r - bexcl;
        int d, rn;
        if (rr <= bc0) { d = 0; rn = rr; }
        else if (rr <= bc0 + bc1) { d = 1; rn = rr - bc0; }
        else if (rr <= bc0 + bc1 + bc2) { d = 2; rn = rr - bc0 - bc1; }
        else { d = 3; rn = rr - bc0 - bc1 - bc2; }
        pref |= (unsigned)(4 * lstar + d) << shift;
        r = rn;
      }
      if (pass < 3) {
        const unsigned msk = 0xFFFFFFFFu << shift;
        const int nshift = shift - 8;
        if (t < S_ / 2) {
          if ((kx & msk) == pref) atomicAdd(&hist[pass + 1][(kx >> nshift) & 255], 1);
          if ((ky & msk) == pref) atomicAdd(&hist[pass + 1][(ky >> nshift) & 255], 1);
        }
      } else {
        if (t < S_ / 2) {
          if (kx <= pref) { const int p = atomicAdd(&lcnt, 1); lists[p] = (uint16_t)(2 * t); }
          if (ky <= pref) { const int p = atomicAdd(&lcnt, 1); lists[p] = (uint16_t)(2 * t + 1); }
        }
      }
      __syncthreads();  // B6..B9
    }

    const int cnt = lcnt;
    const float weight = 1.0f / (float)((cnt > K_) ? cnt : K_);

    // ---- usum partials: u = sum_sel G rows. 8 row-groups x 128 m-pairs ----
    {
      const int rt = t >> 7;
      const int np = t & 127;
      float a0 = 0.0f, a1 = 0.0f;
      for (int p = rt; p < cnt; p += 8) {
        const uint32_t u = GRB[(size_t)lists[p] * (N_ / 2) + np];
        a0 += blo(u);
        a1 += bhi(u);
      }
      *(float2*)&scratch[rt][2 * np] = make_float2(a0, a1);
    }
    __syncthreads();  // B10

    // ---- w update + projection (wave 0), u-reduce fused ----
    if (t < 64) {
      float4 u4 = make_float4(0.0f, 0.0f, 0.0f, 0.0f);
#pragma unroll
      for (int oct = 0; oct < 8; ++oct) {
        const float4 x = *(const float4*)&scratch[oct][4 * ln];
        u4.x += x.x; u4.y += x.y; u4.z += x.z; u4.w += x.w;
      }
      const float lr = 0.5f / sqrtf((float)it + 1.0f);
      const float4 w4 = *(const float4*)(w_s + 4 * ln);
      const float4 m4 = *(const float4*)(muB + 4 * ln);
      float y[4];
      y[0] = w4.x + lr * (muf * m4.x + u4.x * weight);
      y[1] = w4.y + lr * (muf * m4.y + u4.y * weight);
      y[2] = w4.z + lr * (muf * m4.z + u4.z * weight);
      y[3] = w4.w + lr * (muf * m4.w + u4.w * weight);
      proj_store(y, fl_bil, mass, muf, muB, ln, w_s, &c_sh);
    }
    __syncthreads();  // B11 (doubles as next iteration's B1)
  }

  // ---- output (part 0 only): w / (sum + 1e-8) ----
  if (part == 0) {
    if (t < 64) {
      const float4 w4 = *(const float4*)(w_s + 4 * ln);
      const float ssum = wred_f(w4.x + w4.y + w4.z + w4.w);
      if (ln == 0) sum_sh = ssum;
    }
    __syncthreads();
    if (t < N_) out[(size_t)b * N_ + t] = fmaxf(w_s[t], 0.0f) / (sum_sh + 1e-8f);
  }
}

extern "C" void kernel_launch(void* const* d_in, const int* in_sizes, int n_in,
                              void* d_out, int out_size, void* d_ws, size_t ws_size,
                              hipStream_t stream) {
  const float* mu = (const float*)d_in[0];
  const float* sigma = (const float*)d_in[1];
  const float* eps = (const float*)d_in[2];
  const int* crisis = (const int*)d_in[3];
  const int* lam = (const int*)d_in[4];
  float* out = (float*)d_out;
  float* ws = (float*)d_ws;

  uint16_t* Lr16 = (uint16_t*)(ws + OFF_LR16);
  uint16_t* GT16 = (uint16_t*)(ws + OFF_GT);
  uint16_t* GR16 = (uint16_t*)(ws + OFF_GR);
  float* Lc = ws + OFF_GR;  // fp32 L aliases GR slot (dead before g_kernel writes GR)
  unsigned* lossbits = (unsigned*)(ws + OFF_LOSS);
  int* bar = (int*)(ws + OFF_BAR);

  chol_kernel<<<dim3(B_), dim3(512), 0, stream>>>(sigma, Lc);
  lpack_kernel<<<dim3(B_), dim3(256), 0, stream>>>(Lc, Lr16);
  g_kernel<<<dim3(B_, S_ / GS_), dim3(256), 0, stream>>>(eps, Lr16, GT16, GR16, bar);

  solve_kernel<<<dim3(PART_ * B_), dim3(1024), 0, stream>>>(
      mu, crisis, lam, GT16, GR16, lossbits, bar, out);
}

// Round 4
// 4204.947 us; speedup vs baseline: 2.4059x; 1.2136x over previous
//
#include <hip/hip_runtime.h>
#include <stdint.h>

#define B_   64
#define N_   256
#define S_   2000
#define K_   100
#define BIL_ 4
#define NITER_ 200
#define JITTER_ 1e-4f
#define SAFETY_ 0.5f
#define PART_ 4
#define SCH_  (S_ / PART_)   // 500 scenarios per block
#define GS_   50             // scenarios per g_kernel block

// ---- ws layout (offsets in float units) ----
#define OFF_LC16  ((size_t)0)                                   // (unused)
#define OFF_LR16  (OFF_LC16 + (size_t)B_ * N_ * N_ / 2)         // bf16 L row-major
#define OFF_GT    (OFF_LR16 + (size_t)B_ * N_ * N_ / 2)         // bf16 G^T [b][m][s]
#define OFF_GR    (OFF_GT + (size_t)B_ * N_ * S_ / 2)           // bf16 G [b][s][m] (& temp fp32 Lc)
#define OFF_LOSS  (OFF_GR + (size_t)B_ * S_ * N_ / 2)           // uint loss keys, double-buffered
#define OFF_BAR   (OFF_LOSS + (size_t)2 * B_ * S_)              // int barrier counters

// ---------------- helpers ----------------
__device__ __forceinline__ float wred_f(float x) {
#pragma unroll
  for (int off = 32; off > 0; off >>= 1) x += __shfl_xor(x, off);
  return x;
}
__device__ __forceinline__ int wred_i(int x) {
#pragma unroll
  for (int off = 32; off > 0; off >>= 1) x += __shfl_xor(x, off);
  return x;
}
// monotone key: larger loss -> SMALLER key (top-K largest = K smallest keys)
__device__ __forceinline__ unsigned keyd(float x) {
  unsigned u = __float_as_uint(x);
  unsigned ku = (u & 0x80000000u) ? ~u : (u | 0x80000000u);
  return ~ku;
}
__device__ __forceinline__ uint16_t f2b(float f) {  // RNE fp32->bf16
  uint32_t u = __float_as_uint(f);
  uint32_t r = u + 0x7FFFu + ((u >> 16) & 1u);
  return (uint16_t)(r >> 16);
}
__device__ __forceinline__ float blo(uint32_t u) { return __uint_as_float(u << 16); }
__device__ __forceinline__ float bhi(uint32_t u) { return __uint_as_float(u & 0xFFFF0000u); }

// Michelot exact simplex projection (fixed point == reference sort formula); one wave.
__device__ __forceinline__ float michelot4(const float vp[4], float z) {
  bool act[4] = {true, true, true, true};
  float theta = 0.0f;
  int prev = -1;
  for (int pass = 0; pass < 300; ++pass) {
    float ls = 0.0f; int lc = 0;
#pragma unroll
    for (int j = 0; j < 4; ++j) { if (act[j]) { ls += vp[j]; lc += 1; } }
    ls = wred_f(ls);
    lc = wred_i(lc);
    theta = (ls - z) / (float)lc;
    if (lc == prev) break;
    prev = lc;
#pragma unroll
    for (int j = 0; j < 4; ++j) act[j] = (vp[j] > theta);
  }
  return theta;
}

__device__ __forceinline__ void proj_store(const float y[4], float fl_bil, float mass, float muf,
                                           const float* __restrict__ muB, int ln,
                                           float* w_s, float* c_sh) {
  float vp[4];
#pragma unroll
  for (int j = 0; j < 4; ++j) {
    const int n = 4 * ln + j;
    vp[j] = y[j] - ((n == BIL_) ? fl_bil : 0.0f);
  }
  const float theta = michelot4(vp, mass);
  const float4 m4 = *(const float4*)(muB + 4 * ln);
  const float mm[4] = {m4.x, m4.y, m4.z, m4.w};
  float wj[4];
  float cp = 0.0f;
#pragma unroll
  for (int j = 0; j < 4; ++j) {
    const int n = 4 * ln + j;
    wj[j] = fmaxf(vp[j] - theta, 0.0f) + ((n == BIL_) ? fl_bil : 0.0f);
    cp = fmaf(muf * mm[j], wj[j], cp);
  }
  cp = wred_f(cp);
  if (ln == 0) *c_sh = cp;
  *(float4*)(w_s + 4 * ln) = make_float4(wj[0], wj[1], wj[2], wj[3]);
}

// ---------------- Cholesky v3: one block (512 thr) per batch (proven r3) ----------------
__global__ __launch_bounds__(512) void chol_kernel(const float* __restrict__ sigma,
                                                   float* __restrict__ Lc) {
  const int b = blockIdx.x;
  const int tid = threadIdx.x;
  const int i = tid & 255;
  const int half = tid >> 8;
  const float* Sg = sigma + (size_t)b * N_ * N_;
  float* L = Lc + (size_t)b * N_ * N_;
  __shared__ __align__(16) float slab[248 * 8];
  __shared__ __align__(16) float spart[256][8];
  __shared__ __align__(16) float pnl[64];

  for (int j0 = 0; j0 < N_; j0 += 8) {
    for (int x = tid; x < j0 * 8; x += 512) {
      const int k = x >> 3, jj = x & 7;
      slab[x] = L[(size_t)k * N_ + (j0 + jj)];
    }
    float s[8];
    if (half == 0) {
#pragma unroll
      for (int jj = 0; jj < 8; ++jj) {
        float a = Sg[(size_t)(j0 + jj) * N_ + i];
        if (i == j0 + jj) a += JITTER_;
        s[jj] = a;
      }
    } else {
#pragma unroll
      for (int jj = 0; jj < 8; ++jj) s[jj] = 0.0f;
    }
    __syncthreads();

    const int kb = half ? (j0 >> 1) : 0;
    const int ke = half ? j0 : (j0 >> 1);
#pragma unroll 4
    for (int k = kb; k < ke; ++k) {
      const float lk = L[(size_t)k * N_ + i];
      const float4 h0 = *(const float4*)&slab[k * 8];
      const float4 h1 = *(const float4*)&slab[k * 8 + 4];
      s[0] = fmaf(-lk, h0.x, s[0]);
      s[1] = fmaf(-lk, h0.y, s[1]);
      s[2] = fmaf(-lk, h0.z, s[2]);
      s[3] = fmaf(-lk, h0.w, s[3]);
      s[4] = fmaf(-lk, h1.x, s[4]);
      s[5] = fmaf(-lk, h1.y, s[5]);
      s[6] = fmaf(-lk, h1.z, s[6]);
      s[7] = fmaf(-lk, h1.w, s[7]);
    }
    if (half == 1) {
      *(float4*)&spart[i][0] = make_float4(s[0], s[1], s[2], s[3]);
      *(float4*)&spart[i][4] = make_float4(s[4], s[5], s[6], s[7]);
    }
    __syncthreads();

    if (half == 0) {
      const float4 p0 = *(const float4*)&spart[i][0];
      const float4 p1 = *(const float4*)&spart[i][4];
      s[0] += p0.x; s[1] += p0.y; s[2] += p0.z; s[3] += p0.w;
      s[4] += p1.x; s[5] += p1.y; s[6] += p1.z; s[7] += p1.w;
      if ((i >> 3) == (j0 >> 3)) {
        const int base = j0 & 63;
        const int r = i & 7;
        float l[8], di[8];
#pragma unroll
        for (int m = 0; m < 8; ++m) {
          const float smv = __shfl(s[m], base + m);
          const float d = sqrtf(smv);
          const float dinv = 1.0f / d;
          di[m] = dinv;
          float lm;
          if (r == m) lm = d;
          else if (r > m) lm = s[m] * dinv;
          else lm = 0.0f;
          l[m] = lm;
#pragma unroll
          for (int mm = m + 1; mm < 8; ++mm) {
            s[mm] = fmaf(-lm, __shfl(lm, base + mm), s[mm]);
          }
        }
#pragma unroll
        for (int m = 0; m < 8; ++m) pnl[r * 8 + m] = (m < r) ? l[m] : ((m == r) ? di[r] : 0.0f);
#pragma unroll
        for (int m = 0; m < 8; ++m) L[(size_t)(j0 + m) * N_ + i] = l[m];
      }
    }
    __syncthreads();

    if (half == 0 && (i >> 3) != (j0 >> 3)) {
      float l[8];
      if (i > j0) {
#pragma unroll
        for (int m = 0; m < 8; ++m) {
          float sm = s[m];
#pragma unroll
          for (int mm = 0; mm < 8; ++mm) {
            if (mm < m) sm = fmaf(-l[mm], pnl[m * 8 + mm], sm);
          }
          l[m] = sm * pnl[m * 8 + m];
        }
      } else {
#pragma unroll
        for (int m = 0; m < 8; ++m) l[m] = 0.0f;
      }
#pragma unroll
      for (int m = 0; m < 8; ++m) L[(size_t)(j0 + m) * N_ + i] = l[m];
    }
    __syncthreads();
  }
}

// ---------------- pack L (row-major bf16: Lr16[i*N+k] = L[i][k]) ----------------
__global__ __launch_bounds__(256) void lpack_kernel(const float* __restrict__ Lc,
                                                    uint16_t* __restrict__ Lr16) {
  const int b = blockIdx.x;
  const float* Lp = Lc + (size_t)b * N_ * N_;
  uint16_t* R16 = Lr16 + (size_t)b * N_ * N_;
  __shared__ float tl[32][33];
  const int tx = threadIdx.x & 31;
  const int ty = threadIdx.x >> 5;
  for (int kt = 0; kt < 8; ++kt) {
    for (int it = 0; it < 8; ++it) {
#pragma unroll
      for (int rr = 0; rr < 4; ++rr) {
        const int k = kt * 32 + ty + 8 * rr;
        const int ii = it * 32 + tx;
        tl[ty + 8 * rr][tx] = Lp[(size_t)k * N_ + ii];
      }
      __syncthreads();
#pragma unroll
      for (int rr = 0; rr < 4; ++rr) {
        const int ii = it * 32 + ty + 8 * rr;
        const int k = kt * 32 + tx;
        R16[(size_t)ii * N_ + k] = f2b(tl[tx][ty + 8 * rr]);
      }
      __syncthreads();
    }
  }
}

// ---------------- G = eps @ L^T (one-time GEMM, lower-tri aware); zero bar ----------------
// G[s][m] = sum_n L[m][n] * eps[s][n]  (= R without mu). Thread t = asset m, 50 scenarios.
__global__ __launch_bounds__(256) void g_kernel(const float* __restrict__ eps,
                                                const uint16_t* __restrict__ Lr16,
                                                uint16_t* __restrict__ GT16,
                                                uint16_t* __restrict__ GR16,
                                                int* __restrict__ bar) {
  const int b = blockIdx.x;
  const int s0 = blockIdx.y * GS_;
  const int t = threadIdx.x;
  if (b == 0 && blockIdx.y == 0 && t < 64) bar[t] = 0;
  __shared__ __align__(16) uint16_t esh[GS_][N_];  // bf16 eps tile [s][n]
  const float* E = eps + ((size_t)b * S_ + s0) * N_;
  for (int p = 0; p < GS_; ++p) esh[p][t] = f2b(E[(size_t)p * N_ + t]);
  __syncthreads();

  const uint32_t* Lrow = (const uint32_t*)(Lr16 + (size_t)b * N_ * N_) + (size_t)t * (N_ / 2);
  float acc[GS_];
#pragma unroll
  for (int s = 0; s < GS_; ++s) acc[s] = 0.0f;
  const int jmax = (t >> 1) + 1;  // L[m][n] == 0 for n > m
  for (int j = 0; j < jmax; ++j) {
    const uint32_t lu = Lrow[j];
    const float l0 = blo(lu), l1 = bhi(lu);
#pragma unroll
    for (int s = 0; s < GS_; ++s) {
      const uint32_t eu = *(const uint32_t*)&esh[s][2 * j];
      acc[s] = fmaf(l1, bhi(eu), fmaf(l0, blo(eu), acc[s]));
    }
  }
  // GR[s][m]: coalesced across threads
  uint16_t* GRb = GR16 + ((size_t)b * S_ + s0) * N_ + t;
  for (int s = 0; s < GS_; ++s) GRb[(size_t)s * N_] = f2b(acc[s]);
  // GT[m][s]: 25 contiguous u32 per thread (s-pairs packed)
  uint32_t* GTb = (uint32_t*)(GT16 + (size_t)b * N_ * S_ + (size_t)t * S_ + s0);
#pragma unroll
  for (int u = 0; u < GS_ / 2; ++u) {
    const uint32_t pk = (uint32_t)f2b(acc[2 * u]) | ((uint32_t)f2b(acc[2 * u + 1]) << 16);
    GTb[u] = pk;
  }
}

// ---------------- solver: 4 blocks (1024 thr) per batch, grid 256, 1 block/CU ----------------
// r11: G-form with IN-LOOP GT reads (L2/L3-resident after iter 0). r10's register preload
// spilled to scratch twice (VGPR pinned to 64 by the compiler regardless of launch_bounds
// hints; WRITE_SIZE +72MB proved it) -- do NOT preload per-thread arrays >8 elems here.
// Plain launch_bounds(1024): matches r7's proven codegen (in-loop strided L2 reads, no spill).
__global__ __launch_bounds__(1024) void solve_kernel(
    const float* __restrict__ mu, const int* __restrict__ pcrisis,
    const int* __restrict__ plam, const uint16_t* __restrict__ GT16,
    const uint16_t* __restrict__ GR16, unsigned* __restrict__ lossbits,
    int* __restrict__ bar, float* __restrict__ out) {
  const int bx = blockIdx.x;
  const int b = bx & (B_ - 1);
  const int part = bx >> 6;  // 0..3; blocks b+64k land on XCD b%8 under %8 RR
  const int t = threadIdx.x;
  const int ln = t & 63;
  const int s0 = part * SCH_;

  __shared__ __align__(16) float w_s[N_];
  __shared__ __align__(16) float scratch[8][N_];  // loss partials (flat) / usum partials
  __shared__ __align__(16) uint16_t lists[S_];
  __shared__ __align__(16) int hist[4][256];      // one bank per radix pass
  __shared__ float c_sh;
  __shared__ int lcnt;
  __shared__ float sum_sh;

  const int crisis = pcrisis[0];
  const int lamv = plam[0];
  const float muf = 1.0f + ((lamv > 0) ? (1.0f / fmaxf((float)lamv, 0.1f)) : 0.0f);
  const float fl_bil = SAFETY_ * (float)crisis;
  const float mass = 1.0f - fl_bil;

  const float* muB = mu + (size_t)b * N_;
  const uint32_t* GTB = (const uint32_t*)(GT16 + (size_t)b * N_ * S_);
  const uint32_t* GRB = (const uint32_t*)(GR16 + (size_t)b * S_ * N_);
  float* sc1 = &scratch[0][0];

  const int q = t >> 8;     // m-quarter (64 m)
  const int idx = t & 255;  // scenario-pair (idx < 250 active)
  const uint32_t* gcol = GTB + (size_t)(64 * q) * (S_ / 2) + (s0 >> 1) + idx;

  // ---- w0 = proj(uniform) ----
  if (t < 64) {
    float y[4];
#pragma unroll
    for (int j = 0; j < 4; ++j) y[j] = 1.0f / (float)N_;
    proj_store(y, fl_bil, mass, muf, muB, ln, w_s, &c_sh);
  }
  __syncthreads();  // B1

  for (int it = 0; it < NITER_; ++it) {
    // ---- loss partials: a = G_s[64q..64q+63] . w, G read in-loop from L2/L3 ----
    if (idx < SCH_ / 2) {
      float a0 = 0.0f, a1 = 0.0f;
#pragma unroll 8
      for (int j = 0; j < 64; ++j) {
        const uint32_t u = gcol[(size_t)j * (S_ / 2)];
        const float ww = w_s[64 * q + j];  // broadcast
        a0 = fmaf(blo(u), ww, a0);
        a1 = fmaf(bhi(u), ww, a1);
      }
      *(float2*)&sc1[q * SCH_ + 2 * idx] = make_float2(a0, a1);
    }
    __syncthreads();  // B2

    // ---- combine + publish keys (t<500); zero hist banks & lcnt (t>=512) ----
    unsigned* lgbuf = lossbits + ((it & 1) ? (size_t)B_ * S_ : 0) + (size_t)b * S_;
    if (t < SCH_) {
      const float lv = -(c_sh + ((sc1[t] + sc1[SCH_ + t]) + (sc1[2 * SCH_ + t] + sc1[3 * SCH_ + t])));
      __hip_atomic_store(&lgbuf[s0 + t], keyd(lv), __ATOMIC_RELAXED, __HIP_MEMORY_SCOPE_AGENT);
    } else if (t >= 512) {
      for (int x = t - 512; x < 4 * 256; x += 512) ((int*)hist)[x] = 0;
      if (t == 512) lcnt = 0;
    }
    __syncthreads();  // B3 (drains vmcnt before barrier exit)

    // ---- per-batch spin barrier ----
    if (t == 0) {
      __hip_atomic_fetch_add(&bar[b], 1, __ATOMIC_RELAXED, __HIP_MEMORY_SCOPE_AGENT);
      const int target = PART_ * (it + 1);
      while (__hip_atomic_load(&bar[b], __ATOMIC_RELAXED, __HIP_MEMORY_SCOPE_AGENT) < target) {
        __builtin_amdgcn_s_sleep(1);
      }
    }
    __syncthreads();  // B4

    // ---- gather all 2000 keys (thread t owns scenarios 2t, 2t+1) + pass-0 hist ----
    uint32_t kx = 0xFFFFFFFFu, ky = 0xFFFFFFFFu;
    if (t < S_ / 2) {
      const unsigned long long two = __hip_atomic_load(
          (const unsigned long long*)(lgbuf + 2 * t), __ATOMIC_RELAXED, __HIP_MEMORY_SCOPE_AGENT);
      kx = (uint32_t)two;
      ky = (uint32_t)(two >> 32);
      atomicAdd(&hist[0][kx >> 24], 1);
      atomicAdd(&hist[0][ky >> 24], 1);
    }
    __syncthreads();  // B5

    // ---- 4-pass radix select: redundant all-wave scan ----
    unsigned pref = 0;
    int r = K_;
#pragma unroll
    for (int pass = 0; pass < 4; ++pass) {
      const int shift = 24 - 8 * pass;
      {
        const int4 c4 = *(const int4*)&hist[pass][4 * ln];
        const int c0 = c4.x, c1 = c4.y, c2 = c4.z, c3 = c4.w;
        const int tot = c0 + c1 + c2 + c3;
        int sc = tot;
#pragma unroll
        for (int off = 1; off < 64; off <<= 1) {
          const int o = __shfl_up(sc, off);
          if (ln >= off) sc += o;
        }
        const int excl = sc - tot;
        const bool has = (excl < r) && (r <= sc);
        const unsigned long long bal = __ballot(has);
        const int lstar = __ffsll(bal) - 1;
        const int bc0 = __shfl(c0, lstar);
        const int bc1 = __shfl(c1, lstar);
        const int bc2 = __shfl(c2, lstar);
        const int bexcl = __shfl(excl, lstar);
        const int rr = r - bexcl;
        int d, rn;
        if (rr <= bc0) { d = 0; rn = rr; }
        else if (rr <= bc0 + bc1) { d = 1; rn = rr - bc0; }
        else if (rr <= bc0 + bc1 + bc2) { d = 2; rn = rr - bc0 - bc1; }
        else { d = 3; rn = rr - bc0 - bc1 - bc2; }
        pref |= (unsigned)(4 * lstar + d) << shift;
        r = rn;
      }
      if (pass < 3) {
        const unsigned msk = 0xFFFFFFFFu << shift;
        const int nshift = shift - 8;
        if (t < S_ / 2) {
          if ((kx & msk) == pref) atomicAdd(&hist[pass + 1][(kx >> nshift) & 255], 1);
          if ((ky & msk) == pref) atomicAdd(&hist[pass + 1][(ky >> nshift) & 255], 1);
        }
      } else {
        if (t < S_ / 2) {
          if (kx <= pref) { const int p = atomicAdd(&lcnt, 1); lists[p] = (uint16_t)(2 * t); }
          if (ky <= pref) { const int p = atomicAdd(&lcnt, 1); lists[p] = (uint16_t)(2 * t + 1); }
        }
      }
      __syncthreads();  // B6..B9
    }

    const int cnt = lcnt;
    const float weight = 1.0f / (float)((cnt > K_) ? cnt : K_);

    // ---- usum partials: u = sum_sel G rows. 8 row-groups x 128 m-pairs ----
    {
      const int rt = t >> 7;
      const int np = t & 127;
      float a0 = 0.0f, a1 = 0.0f;
      for (int p = rt; p < cnt; p += 8) {
        const uint32_t u = GRB[(size_t)lists[p] * (N_ / 2) + np];
        a0 += blo(u);
        a1 += bhi(u);
      }
      *(float2*)&scratch[rt][2 * np] = make_float2(a0, a1);
    }
    __syncthreads();  // B10

    // ---- w update + projection (wave 0), u-reduce fused ----
    if (t < 64) {
      float4 u4 = make_float4(0.0f, 0.0f, 0.0f, 0.0f);
#pragma unroll
      for (int oct = 0; oct < 8; ++oct) {
        const float4 x = *(const float4*)&scratch[oct][4 * ln];
        u4.x += x.x; u4.y += x.y; u4.z += x.z; u4.w += x.w;
      }
      const float lr = 0.5f / sqrtf((float)it + 1.0f);
      const float4 w4 = *(const float4*)(w_s + 4 * ln);
      const float4 m4 = *(const float4*)(muB + 4 * ln);
      float y[4];
      y[0] = w4.x + lr * (muf * m4.x + u4.x * weight);
      y[1] = w4.y + lr * (muf * m4.y + u4.y * weight);
      y[2] = w4.z + lr * (muf * m4.z + u4.z * weight);
      y[3] = w4.w + lr * (muf * m4.w + u4.w * weight);
      proj_store(y, fl_bil, mass, muf, muB, ln, w_s, &c_sh);
    }
    __syncthreads();  // B11 (doubles as next iteration's B1)
  }

  // ---- output (part 0 only): w / (sum + 1e-8) ----
  if (part == 0) {
    if (t < 64) {
      const float4 w4 = *(const float4*)(w_s + 4 * ln);
      const float ssum = wred_f(w4.x + w4.y + w4.z + w4.w);
      if (ln == 0) sum_sh = ssum;
    }
    __syncthreads();
    if (t < N_) out[(size_t)b * N_ + t] = fmaxf(w_s[t], 0.0f) / (sum_sh + 1e-8f);
  }
}

extern "C" void kernel_launch(void* const* d_in, const int* in_sizes, int n_in,
                              void* d_out, int out_size, void* d_ws, size_t ws_size,
                              hipStream_t stream) {
  const float* mu = (const float*)d_in[0];
  const float* sigma = (const float*)d_in[1];
  const float* eps = (const float*)d_in[2];
  const int* crisis = (const int*)d_in[3];
  const int* lam = (const int*)d_in[4];
  float* out = (float*)d_out;
  float* ws = (float*)d_ws;

  uint16_t* Lr16 = (uint16_t*)(ws + OFF_LR16);
  uint16_t* GT16 = (uint16_t*)(ws + OFF_GT);
  uint16_t* GR16 = (uint16_t*)(ws + OFF_GR);
  float* Lc = ws + OFF_GR;  // fp32 L aliases GR slot (dead before g_kernel writes GR)
  unsigned* lossbits = (unsigned*)(ws + OFF_LOSS);
  int* bar = (int*)(ws + OFF_BAR);

  chol_kernel<<<dim3(B_), dim3(512), 0, stream>>>(sigma, Lc);
  lpack_kernel<<<dim3(B_), dim3(256), 0, stream>>>(Lc, Lr16);
  g_kernel<<<dim3(B_, S_ / GS_), dim3(256), 0, stream>>>(eps, Lr16, GT16, GR16, bar);

  solve_kernel<<<dim3(PART_ * B_), dim3(1024), 0, stream>>>(
      mu, crisis, lam, GT16, GR16, lossbits, bar, out);
}